// Round 1
// baseline (1514.115 us; speedup 1.0000x reference)
//
#include <hip/hip_runtime.h>

// TemporalLogicLayer: out[b,t,o] = max_{s>=t} MLP([cummax(P[b,t..s,:]) | P[b,s,:]])
// MLP: 256 ->(W1,b1,relu) 132 ->(W2,b2,relu) 132 ->(W3,b3) 64, sigmoid(5x)
//
// R1 baseline: fp32 vector-ALU, block = (t, s-chunk of 16), 320 threads.
// Per s-step: 32 rows (batches) x {132,132,64} outputs, thread tile 4j x 4r.
// feats LDS layout [k][r] stride 36 (conflict-free broadcast b128 reads).
// h2 aliased over feats' p-region (rows 128..255) + 4-row spill buffer.
// Cross-chunk max via atomicMax on uint (all outputs sigmoid > 0).

#define TT 128
#define BB 32
#define DD 128
#define HH 132
#define OO 64
#define KK1 256
#define SC 16
#define RP 36
#define NEG_INF_F -1e30f

__global__ __launch_bounds__(320, 2) void tll_main(
    const float* __restrict__ P,
    const float* __restrict__ W1, const float* __restrict__ b1,
    const float* __restrict__ W2, const float* __restrict__ b2,
    const float* __restrict__ W3, const float* __restrict__ b3,
    float* __restrict__ out)
{
    const int t  = blockIdx.x;
    const int c  = blockIdx.y;
    const int s0 = t + c * SC;
    if (s0 >= TT) return;                       // uniform exit, no syncs skipped
    const int send = (s0 + SC < TT) ? (s0 + SC) : TT;

    // feats[k][r]: k<128 = running max m_d, k in 128..255 = P[b,s,d]
    __shared__ float feats[KK1 * RP];           // 36864 B
    __shared__ float h1s[HH * RP];              // 19008 B
    __shared__ float h2x[4 * RP];               // spill rows 128..131 of h2

    const int tid = threadIdx.x;
    const int rb  = tid & 7;                    // 8 row-blocks of 4 rows
    const int jb  = tid >> 3;                   // 0..39; 33 active (L1/L2), 16 (L3)
    const int r0  = rb * 4;
    const int j0  = jb * 4;

    // init running max m = -inf
    for (int idx = tid; idx < BB * DD; idx += 320) {
        int b = idx >> 7, d = idx & 127;
        feats[d * RP + b] = NEG_INF_F;
    }
    __syncthreads();

    // prefix: fold P[:, t..s0-1, :] into m (each thread owns fixed cells -> no sync needed inside)
    for (int s = t; s < s0; ++s) {
        for (int idx = tid; idx < BB * DD; idx += 320) {
            int b = idx >> 7, d = idx & 127;
            float p = P[(size_t)b * (TT * DD) + (size_t)s * DD + d];
            int a = d * RP + b;
            feats[a] = fmaxf(feats[a], p);
        }
    }
    __syncthreads();

    float rm[4][4];
    #pragma unroll
    for (int jj = 0; jj < 4; ++jj)
        #pragma unroll
        for (int rr = 0; rr < 4; ++rr) rm[jj][rr] = 0.0f;   // sigmoid > 0, safe identity

    for (int s = s0; s < send; ++s) {
        // ---- stage: m = max(m, P[s]); p = P[s] ----
        for (int idx = tid; idx < BB * DD; idx += 320) {
            int b = idx >> 7, d = idx & 127;
            float p = P[(size_t)b * (TT * DD) + (size_t)s * DD + d];
            float m = fmaxf(feats[d * RP + b], p);
            feats[d * RP + b] = m;
            feats[(DD + d) * RP + b] = p;
        }
        __syncthreads();

        // ---- L1: h1 = relu(feats @ W1 + b1), K=256, J=132 (33 jb x 4) ----
        if (jb < 33) {
            float acc[4][4];
            float4 bv = *(const float4*)&b1[j0];
            #pragma unroll
            for (int jj = 0; jj < 4; ++jj) {
                float bb = ((const float*)&bv)[jj];
                #pragma unroll
                for (int rr = 0; rr < 4; ++rr) acc[jj][rr] = bb;
            }
            #pragma unroll 4
            for (int k = 0; k < KK1; ++k) {
                float4 f = *(const float4*)&feats[k * RP + r0];
                float4 w = *(const float4*)&W1[k * HH + j0];
                #pragma unroll
                for (int jj = 0; jj < 4; ++jj) {
                    float wv = ((const float*)&w)[jj];
                    #pragma unroll
                    for (int rr = 0; rr < 4; ++rr)
                        acc[jj][rr] = fmaf(wv, ((const float*)&f)[rr], acc[jj][rr]);
                }
            }
            #pragma unroll
            for (int jj = 0; jj < 4; ++jj) {
                float4 o4;
                o4.x = fmaxf(acc[jj][0], 0.0f);
                o4.y = fmaxf(acc[jj][1], 0.0f);
                o4.z = fmaxf(acc[jj][2], 0.0f);
                o4.w = fmaxf(acc[jj][3], 0.0f);
                *(float4*)&h1s[(j0 + jj) * RP + r0] = o4;
            }
        }
        __syncthreads();

        // ---- L2: h2 = relu(h1 @ W2 + b2), K=132, J=132; h2 -> feats p-region / h2x ----
        if (jb < 33) {
            float acc[4][4];
            float4 bv = *(const float4*)&b2[j0];
            #pragma unroll
            for (int jj = 0; jj < 4; ++jj) {
                float bb = ((const float*)&bv)[jj];
                #pragma unroll
                for (int rr = 0; rr < 4; ++rr) acc[jj][rr] = bb;
            }
            #pragma unroll 4
            for (int k = 0; k < HH; ++k) {
                float4 f = *(const float4*)&h1s[k * RP + r0];
                float4 w = *(const float4*)&W2[k * HH + j0];
                #pragma unroll
                for (int jj = 0; jj < 4; ++jj) {
                    float wv = ((const float*)&w)[jj];
                    #pragma unroll
                    for (int rr = 0; rr < 4; ++rr)
                        acc[jj][rr] = fmaf(wv, ((const float*)&f)[rr], acc[jj][rr]);
                }
            }
            #pragma unroll
            for (int jj = 0; jj < 4; ++jj) {
                float4 o4;
                o4.x = fmaxf(acc[jj][0], 0.0f);
                o4.y = fmaxf(acc[jj][1], 0.0f);
                o4.z = fmaxf(acc[jj][2], 0.0f);
                o4.w = fmaxf(acc[jj][3], 0.0f);
                int jrow = j0 + jj;
                float* dst = (jrow < 128) ? &feats[(DD + jrow) * RP + r0]
                                          : &h2x[(jrow - 128) * RP + r0];
                *(float4*)dst = o4;
            }
        }
        __syncthreads();

        // ---- L3: y = sigmoid(5*(h2 @ W3 + b3)), K=132, J=64 (16 jb x 4) ----
        if (jb < 16) {
            float acc[4][4];
            float4 bv = *(const float4*)&b3[j0];
            #pragma unroll
            for (int jj = 0; jj < 4; ++jj) {
                float bb = ((const float*)&bv)[jj];
                #pragma unroll
                for (int rr = 0; rr < 4; ++rr) acc[jj][rr] = bb;
            }
            #pragma unroll 4
            for (int k = 0; k < 128; ++k) {
                float4 f = *(const float4*)&feats[(DD + k) * RP + r0];
                float4 w = *(const float4*)&W3[k * OO + j0];
                #pragma unroll
                for (int jj = 0; jj < 4; ++jj) {
                    float wv = ((const float*)&w)[jj];
                    #pragma unroll
                    for (int rr = 0; rr < 4; ++rr)
                        acc[jj][rr] = fmaf(wv, ((const float*)&f)[rr], acc[jj][rr]);
                }
            }
            #pragma unroll
            for (int k = 128; k < HH; ++k) {
                float4 f = *(const float4*)&h2x[(k - 128) * RP + r0];
                float4 w = *(const float4*)&W3[k * OO + j0];
                #pragma unroll
                for (int jj = 0; jj < 4; ++jj) {
                    float wv = ((const float*)&w)[jj];
                    #pragma unroll
                    for (int rr = 0; rr < 4; ++rr)
                        acc[jj][rr] = fmaf(wv, ((const float*)&f)[rr], acc[jj][rr]);
                }
            }
            #pragma unroll
            for (int jj = 0; jj < 4; ++jj)
                #pragma unroll
                for (int rr = 0; rr < 4; ++rr) {
                    float y = 1.0f / (1.0f + __expf(-5.0f * acc[jj][rr]));
                    rm[jj][rr] = fmaxf(rm[jj][rr], y);
                }
        }
        __syncthreads();   // protect h2 region (feats) before next stage
    }

    if (jb < 16) {
        #pragma unroll
        for (int jj = 0; jj < 4; ++jj)
            #pragma unroll
            for (int rr = 0; rr < 4; ++rr) {
                int j = j0 + jj, b = r0 + rr;
                atomicMax((unsigned int*)&out[(size_t)b * (TT * OO) + t * OO + j],
                          __float_as_uint(rm[jj][rr]));
            }
    }
}

extern "C" void kernel_launch(void* const* d_in, const int* in_sizes, int n_in,
                              void* d_out, int out_size, void* d_ws, size_t ws_size,
                              hipStream_t stream) {
    const float* P  = (const float*)d_in[0];
    const float* W1 = (const float*)d_in[1];
    const float* b1 = (const float*)d_in[2];
    const float* W2 = (const float*)d_in[3];
    const float* b2 = (const float*)d_in[4];
    const float* W3 = (const float*)d_in[5];
    const float* b3 = (const float*)d_in[6];
    float* out = (float*)d_out;

    // out is re-poisoned before every launch; atomicMax needs 0-init (all y > 0)
    hipMemsetAsync(out, 0, (size_t)out_size * sizeof(float), stream);

    dim3 grid(TT, (TT + SC - 1) / SC);   // (128, 8); blocks with s0 >= T exit
    tll_main<<<grid, 320, 0, stream>>>(P, W1, b1, W2, b2, W3, b3, out);
}

// Round 2
// 288.359 us; speedup vs baseline: 5.2508x; 5.2508x over previous
//
#include <hip/hip_runtime.h>

// TemporalLogicLayer R2: f16 MFMA (16x16x32) for all three MLP layers.
// out[b,t,o] = max_{s>=t} sigmoid(5*(relu(relu([cummax(P[t..s])|P[s]]W1+b1)W2+b2)W3+b3))
//
// Structure: block = (t, s-chunk of 16), 256 threads = 4 waves.
// - prep kernel: W -> transposed f16 Wt[n][k] in d_ws, N-padded to 160, K-padded
//   to 160 with zeros (zero pad cols in W make padded h entries harmless).
// - running max over s held in REGISTERS (each thread owns 16 (b,d) cells),
//   written per s-step to feats LDS in MFMA A-layout (f16, row stride 264).
// - each wave computes BOTH 16-row M-tiles (halves weight re-read traffic) and
//   a (3,3,2,2) split of the ten 16-col N-tiles (wave-uniform branch, no arrays
//   indexed by runtime nt -> no scratch spill).
// - 3 barriers per s-step (stage->L1->L2->L3 ring; L3/next-stage need none).
// - cross-chunk max via atomicMax on uint (sigmoid outputs > 0), out memset 0.

#define TT 128
#define BB 32
#define DD 128
#define OO 64
#define SC 16
#define FS 264      // feats row stride (f16 elems): 256 data + 8 pad (2-way banks)
#define HS 168      // h1/h2 row stride: 160 data + 8 pad
#define NEG_INF_F -1e30f

typedef __attribute__((ext_vector_type(8))) _Float16 half8;
typedef __attribute__((ext_vector_type(4))) float f32x4;

// d_ws layout (bytes)
#define W1T_OFF 0                        // f16 [160][256]
#define W2T_OFF (160*256*2)              // f16 [160][160]
#define W3T_OFF (W2T_OFF + 160*160*2)    // f16 [64][160]
#define B1P_OFF (W3T_OFF + 64*160*2)     // f32 [160]
#define B2P_OFF (B1P_OFF + 160*4)        // f32 [160]
#define WS_NEED (B2P_OFF + 160*4)        // = 154880 B

union H8 { _Float16 h[8]; half8 v; };

__global__ void tll_prep(const float* __restrict__ W1, const float* __restrict__ b1,
                         const float* __restrict__ W2, const float* __restrict__ b2,
                         const float* __restrict__ W3, char* __restrict__ ws) {
    _Float16* W1t = (_Float16*)(ws + W1T_OFF);
    _Float16* W2t = (_Float16*)(ws + W2T_OFF);
    _Float16* W3t = (_Float16*)(ws + W3T_OFF);
    float*    b1p = (float*)(ws + B1P_OFF);
    float*    b2p = (float*)(ws + B2P_OFF);
    int idx = blockIdx.x * 256 + threadIdx.x;          // 160 blocks -> 40960 thr
    if (idx < 160*256) {                               // W1t[n][k], n<132 real
        int n = idx >> 8, k = idx & 255;
        float v = (n < 132) ? W1[k*132 + n] : 0.f;
        W1t[idx] = (_Float16)v;
    }
    if (idx < 160*160) {                               // W2t[n][k]
        int n = idx / 160, k = idx - n*160;
        float v = (n < 132 && k < 132) ? W2[k*132 + n] : 0.f;
        W2t[idx] = (_Float16)v;
    }
    if (idx < 64*160) {                                // W3t[o][k]
        int o = idx / 160, k = idx - o*160;
        float v = (k < 132) ? W3[k*64 + o] : 0.f;
        W3t[idx] = (_Float16)v;
    }
    if (idx < 160) {
        b1p[idx] = (idx < 132) ? b1[idx] : 0.f;
        b2p[idx] = (idx < 132) ? b2[idx] : 0.f;
    }
}

#define MFMA(A, B, C) __builtin_amdgcn_mfma_f32_16x16x32_f16((A), (B), (C), 0, 0, 0)

// one 16-col N-tile of a layer: 2 M-tiles, KK k-steps against preloaded a0/a1
#define GEMM_TILE(WT, STRIDE, N0, KOFF, KK, ACC0, ACC1)                          \
    {                                                                            \
        const _Float16* wp = (WT) + (size_t)((N0) + ln) * (STRIDE) + (KOFF) + q*8;\
        _Pragma("unroll")                                                        \
        for (int kk = 0; kk < (KK); ++kk) {                                      \
            half8 bf = *(const half8*)(wp + kk*32);                              \
            ACC0 = MFMA(a0[kk], bf, ACC0);                                       \
            ACC1 = MFMA(a1[kk], bf, ACC1);                                       \
        }                                                                        \
    }

// relu+bias epilogue into an h buffer (A-layout, stride HS)
#define EPI_RELU(HBUF, N0, ACC0, ACC1, BIAS)                                     \
    {                                                                            \
        int n = (N0) + ln;                                                       \
        _Pragma("unroll")                                                        \
        for (int r = 0; r < 4; ++r) {                                            \
            HBUF[(q*4 + r)*HS + n]      = (_Float16)fmaxf(ACC0[r] + (BIAS), 0.f);\
            HBUF[(16 + q*4 + r)*HS + n] = (_Float16)fmaxf(ACC1[r] + (BIAS), 0.f);\
        }                                                                        \
    }

__global__ __launch_bounds__(256, 3) void tll_mfma(
    const float* __restrict__ P, const float* __restrict__ b3,
    const char* __restrict__ ws, unsigned int* __restrict__ outU)
{
    const int t  = blockIdx.x;
    const int s0 = t + blockIdx.y * SC;
    if (s0 >= TT) return;                       // uniform exit before any barrier
    const int send = (s0 + SC < TT) ? (s0 + SC) : TT;

    const _Float16* W1t = (const _Float16*)(ws + W1T_OFF);
    const _Float16* W2t = (const _Float16*)(ws + W2T_OFF);
    const _Float16* W3t = (const _Float16*)(ws + W3T_OFF);
    const float*    b1p = (const float*)(ws + B1P_OFF);
    const float*    b2p = (const float*)(ws + B2P_OFF);

    __shared__ _Float16 feats[32 * FS];         // 16896 B, A-matrix of L1
    __shared__ _Float16 h1s[32 * HS];           // 10752 B
    __shared__ _Float16 h2s[32 * HS];           // 10752 B  (total 38400 B)

    const int tid  = threadIdx.x;
    const int lane = tid & 63;
    const int w    = tid >> 6;                  // wave 0..3
    const int ln   = lane & 15;                 // MFMA row/col-in-tile
    const int q    = lane >> 4;                 // MFMA quad

    // N-tile split over 10 tiles (N=160): waves get (3,3,2,2)
    const bool has3   = (w < 2);
    const int  nstart = has3 ? w*3 : 6 + (w - 2)*2;
    const int  n0A = (nstart + 0) * 16;
    const int  n0B = (nstart + 1) * 16;
    const int  n0C = (nstart + 2) * 16;         // only if has3

    // staging ownership: 16 consecutive d per thread
    const int sb = tid >> 3;                    // batch 0..31
    const int d0 = (tid & 7) * 16;

    // preload biases (L2-resident, once per block)
    const float biasA1 = b1p[n0A + ln], biasB1 = b1p[n0B + ln];
    const float biasC1 = has3 ? b1p[n0C + ln] : 0.f;
    const float biasA2 = b2p[n0A + ln], biasB2 = b2p[n0B + ln];
    const float biasC2 = has3 ? b2p[n0C + ln] : 0.f;
    const int   o_     = w*16 + ln;             // L3: one N-tile per wave
    const float bias3  = b3[o_];

    // running max in registers
    f32x4 m[4];
    #pragma unroll
    for (int i = 0; i < 4; ++i) m[i] = (f32x4){NEG_INF_F, NEG_INF_F, NEG_INF_F, NEG_INF_F};

    const float* Pb = P + (size_t)sb * TT * DD + d0;
    for (int s = t; s < s0; ++s) {              // prefix fold (registers only)
        const float* ps = Pb + (size_t)s * DD;
        #pragma unroll
        for (int i = 0; i < 4; ++i) {
            f32x4 p = *(const f32x4*)(ps + i*4);
            m[i].x = fmaxf(m[i].x, p.x); m[i].y = fmaxf(m[i].y, p.y);
            m[i].z = fmaxf(m[i].z, p.z); m[i].w = fmaxf(m[i].w, p.w);
        }
    }

    float rm0[4] = {0.f, 0.f, 0.f, 0.f};        // sigmoid > 0 -> 0 is identity
    float rm1[4] = {0.f, 0.f, 0.f, 0.f};

    for (int s = s0; s < send; ++s) {
        // ---- stage: m = max(m, P[s]); feats = [f16(m) | f16(P[s])] ----
        {
            const float* ps = Pb + (size_t)s * DD;
            f32x4 p[4];
            #pragma unroll
            for (int i = 0; i < 4; ++i) {
                p[i] = *(const f32x4*)(ps + i*4);
                m[i].x = fmaxf(m[i].x, p[i].x); m[i].y = fmaxf(m[i].y, p[i].y);
                m[i].z = fmaxf(m[i].z, p[i].z); m[i].w = fmaxf(m[i].w, p[i].w);
            }
            H8 u;
            u.h[0]=(_Float16)m[0].x; u.h[1]=(_Float16)m[0].y; u.h[2]=(_Float16)m[0].z; u.h[3]=(_Float16)m[0].w;
            u.h[4]=(_Float16)m[1].x; u.h[5]=(_Float16)m[1].y; u.h[6]=(_Float16)m[1].z; u.h[7]=(_Float16)m[1].w;
            *(half8*)&feats[sb*FS + d0] = u.v;
            u.h[0]=(_Float16)m[2].x; u.h[1]=(_Float16)m[2].y; u.h[2]=(_Float16)m[2].z; u.h[3]=(_Float16)m[2].w;
            u.h[4]=(_Float16)m[3].x; u.h[5]=(_Float16)m[3].y; u.h[6]=(_Float16)m[3].z; u.h[7]=(_Float16)m[3].w;
            *(half8*)&feats[sb*FS + d0 + 8] = u.v;
            u.h[0]=(_Float16)p[0].x; u.h[1]=(_Float16)p[0].y; u.h[2]=(_Float16)p[0].z; u.h[3]=(_Float16)p[0].w;
            u.h[4]=(_Float16)p[1].x; u.h[5]=(_Float16)p[1].y; u.h[6]=(_Float16)p[1].z; u.h[7]=(_Float16)p[1].w;
            *(half8*)&feats[sb*FS + 128 + d0] = u.v;
            u.h[0]=(_Float16)p[2].x; u.h[1]=(_Float16)p[2].y; u.h[2]=(_Float16)p[2].z; u.h[3]=(_Float16)p[2].w;
            u.h[4]=(_Float16)p[3].x; u.h[5]=(_Float16)p[3].y; u.h[6]=(_Float16)p[3].z; u.h[7]=(_Float16)p[3].w;
            *(half8*)&feats[sb*FS + 128 + d0 + 8] = u.v;
        }
        __syncthreads();

        // ---- L1: h1 = relu(feats @ W1 + b1), K=256 (two halves of 4 k-steps) ----
        {
            f32x4 z = (f32x4){0.f, 0.f, 0.f, 0.f};
            f32x4 accA0 = z, accA1 = z, accB0 = z, accB1 = z, accC0 = z, accC1 = z;
            #pragma unroll
            for (int half = 0; half < 2; ++half) {
                half8 a0[4], a1[4];
                #pragma unroll
                for (int kk = 0; kk < 4; ++kk) {
                    int koff = (half*4 + kk)*32 + q*8;
                    a0[kk] = *(const half8*)&feats[ln*FS + koff];
                    a1[kk] = *(const half8*)&feats[(16 + ln)*FS + koff];
                }
                GEMM_TILE(W1t, 256, n0A, half*128, 4, accA0, accA1);
                GEMM_TILE(W1t, 256, n0B, half*128, 4, accB0, accB1);
                if (has3) GEMM_TILE(W1t, 256, n0C, half*128, 4, accC0, accC1);
            }
            EPI_RELU(h1s, n0A, accA0, accA1, biasA1);
            EPI_RELU(h1s, n0B, accB0, accB1, biasB1);
            if (has3) EPI_RELU(h1s, n0C, accC0, accC1, biasC1);
        }
        __syncthreads();

        // ---- L2: h2 = relu(h1 @ W2 + b2), K=160 (5 k-steps) ----
        {
            half8 a0[5], a1[5];
            #pragma unroll
            for (int kk = 0; kk < 5; ++kk) {
                int koff = kk*32 + q*8;
                a0[kk] = *(const half8*)&h1s[ln*HS + koff];
                a1[kk] = *(const half8*)&h1s[(16 + ln)*HS + koff];
            }
            f32x4 z = (f32x4){0.f, 0.f, 0.f, 0.f};
            f32x4 accA0 = z, accA1 = z, accB0 = z, accB1 = z, accC0 = z, accC1 = z;
            GEMM_TILE(W2t, 160, n0A, 0, 5, accA0, accA1);
            GEMM_TILE(W2t, 160, n0B, 0, 5, accB0, accB1);
            if (has3) GEMM_TILE(W2t, 160, n0C, 0, 5, accC0, accC1);
            EPI_RELU(h2s, n0A, accA0, accA1, biasA2);
            EPI_RELU(h2s, n0B, accB0, accB1, biasB2);
            if (has3) EPI_RELU(h2s, n0C, accC0, accC1, biasC2);
        }
        __syncthreads();

        // ---- L3: y = sigmoid(5*(h2 @ W3 + b3)); rm = max(rm, y) ----
        {
            half8 a0[5], a1[5];
            #pragma unroll
            for (int kk = 0; kk < 5; ++kk) {
                int koff = kk*32 + q*8;
                a0[kk] = *(const half8*)&h2s[ln*HS + koff];
                a1[kk] = *(const half8*)&h2s[(16 + ln)*HS + koff];
            }
            f32x4 y0 = (f32x4){0.f, 0.f, 0.f, 0.f}, y1 = y0;
            GEMM_TILE(W3t, 160, w*16, 0, 5, y0, y1);
            #pragma unroll
            for (int r = 0; r < 4; ++r) {
                float ya = 1.f / (1.f + __expf(-5.f * (y0[r] + bias3)));
                float yb = 1.f / (1.f + __expf(-5.f * (y1[r] + bias3)));
                rm0[r] = fmaxf(rm0[r], ya);
                rm1[r] = fmaxf(rm1[r], yb);
            }
        }
        // no barrier needed: next stage touches only feats, and every wave has
        // already passed B2/B3 since the last feats read (L1).
    }

    #pragma unroll
    for (int r = 0; r < 4; ++r) {
        int b0 = q*4 + r, b1_ = 16 + q*4 + r;
        atomicMax(&outU[(size_t)b0  * TT * OO + t*OO + o_], __float_as_uint(rm0[r]));
        atomicMax(&outU[(size_t)b1_ * TT * OO + t*OO + o_], __float_as_uint(rm1[r]));
    }
}

extern "C" void kernel_launch(void* const* d_in, const int* in_sizes, int n_in,
                              void* d_out, int out_size, void* d_ws, size_t ws_size,
                              hipStream_t stream) {
    const float* P  = (const float*)d_in[0];
    const float* W1 = (const float*)d_in[1];
    const float* b1 = (const float*)d_in[2];
    const float* W2 = (const float*)d_in[3];
    const float* b2 = (const float*)d_in[4];
    const float* W3 = (const float*)d_in[5];
    const float* b3 = (const float*)d_in[6];

    tll_prep<<<160, 256, 0, stream>>>(W1, b1, W2, b2, W3, (char*)d_ws);
    hipMemsetAsync(d_out, 0, (size_t)out_size * sizeof(float), stream);

    dim3 grid(TT, (TT + SC - 1) / SC);          // (128, 8); s0 >= T blocks exit
    tll_mfma<<<grid, 256, 0, stream>>>(P, b3, (const char*)d_ws,
                                       (unsigned int*)d_out);
}